// Round 5
// baseline (915.712 us; speedup 1.0000x reference)
//
#include <hip/hip_runtime.h>

// Problem dims
#define BB 32
#define TT 2048
#define FF 400
#define HH 1152
#define HH2 576       // HH/2
#define MM 65536      // BB*TT
#define NN 3456       // 3*HH
#define KK 800        // 2*FF
#define MT2 256       // MM/256  (BM=256)
#define NT 27         // NN/128  (BN=128)
#define KTL 25        // KK/32   (BK=32)
#define CH 16         // scan chunks
#define CL 128        // TT/CH

typedef __attribute__((ext_vector_type(8))) short short8;
typedef __attribute__((ext_vector_type(4))) float f32x4;
typedef _Float16 h2 __attribute__((ext_vector_type(2)));
typedef float f2 __attribute__((ext_vector_type(2)));

__device__ __forceinline__ unsigned short f2bf(float f) {
  union { float f; unsigned u; } v; v.f = f;
  unsigned r = v.u + 0x7FFFu + ((v.u >> 16) & 1u);
  return (unsigned short)(r >> 16);
}

__device__ __forceinline__ void async16(void* lds, const void* g) {
  __builtin_amdgcn_global_load_lds((const __attribute__((address_space(1))) void*)g,
                                   (__attribute__((address_space(3))) void*)lds, 16, 0, 0);
}

// W [800][3456] fp32 -> bf16 tiled [nt][kt][kg(4)][n(128)][8]
__global__ __launch_bounds__(256) void pack_W_k(const float* __restrict__ W,
                                                unsigned short* __restrict__ Wws) {
  const int nt = blockIdx.x, kt = blockIdx.y;
  for (int c = threadIdx.x; c < 512; c += 256) {
    const int kg = c >> 7, n = c & 127;
    const int g = nt * 128 + n;
    const int k0 = kt * 32 + kg * 8;
    short8 o;
#pragma unroll
    for (int j = 0; j < 8; ++j) o[j] = (short)f2bf(W[(size_t)(k0 + j) * NN + g]);
    *(short8*)(Wws + ((size_t)(nt * KTL + kt) * 512 + c) * 8) = o;
  }
}

// merged = [x_t | x_{t-1}] -> bf16 tiled [mt][kt][kg(4)][mm(256)][8]
__global__ __launch_bounds__(256) void pack_A_k(const float* __restrict__ x,
                                                unsigned short* __restrict__ Aws) {
  const int mt = blockIdx.x, kt = blockIdx.y;
  for (int c = threadIdx.x; c < 1024; c += 256) {
    const int kg = c >> 8, mm = c & 255;
    const int m = mt * 256 + mm;
    const int b = m >> 11, t = m & 2047;
    const int k = kt * 32 + kg * 8;
    short8 o;
    const float* src = nullptr;
    if (k < FF) src = x + (size_t)(b * TT + t) * FF + k;
    else if (t > 0) src = x + (size_t)(b * TT + t - 1) * FF + (k - FF);
    if (src) {
      f32x4 v0 = *(const f32x4*)(src);
      f32x4 v1 = *(const f32x4*)(src + 4);
#pragma unroll
      for (int j = 0; j < 4; ++j) o[j] = (short)f2bf(v0[j]);
#pragma unroll
      for (int j = 0; j < 4; ++j) o[4 + j] = (short)f2bf(v1[j]);
    } else {
#pragma unroll
      for (int j = 0; j < 8; ++j) o[j] = 0;
    }
    *(short8*)(Aws + ((size_t)(mt * KTL + kt) * 1024 + c) * 8) = o;
  }
}

// C = A(bf16) * W(bf16), 256x128 tile, 8 waves (4M x 2N), BK=32,
// TRIPLE-buffered LDS (72 KB -> 2 blocks/CU), 2-deep prefetch, counted vmcnt.
// All staging issues are uniform across the 512 threads (lane x 16B linear —
// required by global_load_lds; R4's divergent 256-thread B-issue was the bug).
__global__ __launch_bounds__(512, 4) void gemm_k(const unsigned short* __restrict__ Aws,
                                                 const unsigned short* __restrict__ Wws,
                                                 const float* __restrict__ bias,
                                                 _Float16* __restrict__ Zh,
                                                 _Float16* __restrict__ Fh,
                                                 _Float16* __restrict__ Oh) {
  __shared__ unsigned short As[3][8192];  // [kg(4)][mm(256)][8] per buffer (16 KB)
  __shared__ unsigned short Bs[3][4096];  // [kg(4)][n(128)][8]          (8 KB)

  // XCD-bijective swizzle: 6912 = 8 XCDs x 864; nt-fastest within an XCD.
  const int bid = blockIdx.x;
  const int swz = (bid & 7) * 864 + (bid >> 3);
  const int mt = swz / 27;
  const int nt = swz - mt * 27;

  const int tid = threadIdx.x;
  const int lane = tid & 63, w = tid >> 6;
  const int wr = w >> 1, wc = w & 1;          // 4 M-waves x 2 N-waves
  const int l15 = lane & 15, kg = lane >> 4;

  const unsigned short* ga = Aws + (size_t)mt * KTL * 8192;
  const unsigned short* gb = Wws + (size_t)nt * KTL * 4096;

  f32x4 acc[4][4] = {};

  // prologue: stage tiles 0 and 1 (3 issues each: A x2, B x1; all 512 threads)
#pragma unroll
  for (int t = 0; t < 2; ++t) {
    const unsigned short* a = ga + t * 8192;
    const unsigned short* b = gb + t * 4096;
    async16(&As[t][tid * 8], a + tid * 8);
    async16(&As[t][4096 + tid * 8], a + 4096 + tid * 8);
    async16(&Bs[t][tid * 8], b + tid * 8);
  }

#pragma unroll 1
  for (int t = 0; t < KTL; ++t) {
    const int buf = t % 3;
    // wait for tile t's 3 loads (oldest); keep tile t+1's 3 in flight
    if (t < KTL - 1) asm volatile("s_waitcnt vmcnt(3)" ::: "memory");
    else             asm volatile("s_waitcnt vmcnt(0)" ::: "memory");
    __builtin_amdgcn_s_barrier();

    // stage tile t+2 into buf (t+2)%3 == (t-1)%3 (t-1 reads fenced by barrier)
    if (t + 2 < KTL) {
      const int nbuf = (t + 2) % 3;
      const unsigned short* a = ga + (size_t)(t + 2) * 8192;
      const unsigned short* b = gb + (size_t)(t + 2) * 4096;
      async16(&As[nbuf][tid * 8], a + tid * 8);
      async16(&As[nbuf][4096 + tid * 8], a + 4096 + tid * 8);
      async16(&Bs[nbuf][tid * 8], b + tid * 8);
    }

    short8 af[4], bfv[4];
#pragma unroll
    for (int mr = 0; mr < 4; ++mr)
      af[mr] = *(const short8*)&As[buf][(size_t)(kg * 256 + wr * 64 + mr * 16 + l15) * 8];
#pragma unroll
    for (int nr = 0; nr < 4; ++nr)
      bfv[nr] = *(const short8*)&Bs[buf][(size_t)(kg * 128 + wc * 64 + nr * 16 + l15) * 8];

    __builtin_amdgcn_s_setprio(1);
#pragma unroll
    for (int mr = 0; mr < 4; ++mr)
#pragma unroll
      for (int nr = 0; nr < 4; ++nr)
        acc[mr][nr] = __builtin_amdgcn_mfma_f32_16x16x32_bf16(af[mr], bfv[nr], acc[mr][nr], 0, 0, 0);
    __builtin_amdgcn_s_setprio(0);
  }

  // epilogue: bias + activation -> fp16 gate buffers (block is one gate sector: 1152=9*128)
  const int sector = nt / 9;  // 0=z, 1=f, 2=o
  _Float16* __restrict__ dst = (sector == 0) ? Zh : ((sector == 1) ? Fh : Oh);
  const int gbase = nt * 128 + wc * 64 + l15;
  const int colbase = gbase - sector * 1152;
#pragma unroll
  for (int nr = 0; nr < 4; ++nr) {
    const float bv = bias[gbase + nr * 16];
    const int col = colbase + nr * 16;
#pragma unroll
    for (int mr = 0; mr < 4; ++mr) {
      const int row0 = mt * 256 + wr * 64 + mr * 16 + kg * 4;
      f32x4 v = acc[mr][nr];
#pragma unroll
      for (int r = 0; r < 4; ++r) {
        float xv = v[r] + bv;
        float s;
        if (sector == 0) {
          float e = __expf(2.0f * xv);   // tanh(x) = 1 - 2/(e^{2x}+1)
          s = 1.0f - 2.0f / (e + 1.0f);
        } else {
          s = 1.0f / (1.0f + __expf(-xv));
        }
        __builtin_nontemporal_store((_Float16)s, &dst[(size_t)(row0 + r) * HH + col]);
      }
    }
  }
}

// ---- chunked parallel scan of h_t = (1-f)h + f z ----
// pass 1: per (b, chunk, h-pair): compose (P = prod(1-f), Q) over the chunk
__global__ __launch_bounds__(256) void scan1_k(const h2* __restrict__ Zh,
                                               const h2* __restrict__ Fh,
                                               f32x4* __restrict__ PQ) {
  const int idx = blockIdx.x * 256 + threadIdx.x;   // [b][c][hp]
  const int b = idx / (CH * HH2);
  const int r = idx - b * (CH * HH2);
  const int c = r / HH2;
  const int hp = r - c * HH2;
  size_t p = ((size_t)b * TT + (size_t)c * CL) * HH2 + hp;
  float P0 = 1.f, Q0 = 0.f, P1 = 1.f, Q1 = 0.f;
#pragma unroll 8
  for (int t = 0; t < CL; ++t, p += HH2) {
    h2 f = Fh[p], z = Zh[p];
    float f0 = (float)f[0], f1 = (float)f[1];
    float a0 = 1.f - f0, a1 = 1.f - f1;
    P0 *= a0; Q0 = a0 * Q0 + f0 * (float)z[0];
    P1 *= a1; Q1 = a1 * Q1 + f1 * (float)z[1];
  }
  f32x4 o; o[0] = P0; o[1] = Q0; o[2] = P1; o[3] = Q1;
  PQ[idx] = o;
}

// pass 2: sequential over the 16 chunks per (b,h-pair): start states
__global__ __launch_bounds__(256) void scan2_k(const f32x4* __restrict__ PQ,
                                               const float* __restrict__ h0,
                                               f2* __restrict__ Hs) {
  const int idx = blockIdx.x * 256 + threadIdx.x;   // [b][hp]
  const int b = idx / HH2, hp = idx - b * HH2;
  float hc0 = h0[b * HH + hp * 2];
  float hc1 = h0[b * HH + hp * 2 + 1];
#pragma unroll
  for (int c = 0; c < CH; ++c) {
    f2 hs; hs[0] = hc0; hs[1] = hc1;
    Hs[((size_t)b * CH + c) * HH2 + hp] = hs;
    f32x4 pq = PQ[((size_t)b * CH + c) * HH2 + hp];
    hc0 = pq[0] * hc0 + pq[1];
    hc1 = pq[2] * hc1 + pq[3];
  }
}

// pass 3: recompute within chunk from start state (exact sequential fmaf form), c = o*h
__global__ __launch_bounds__(256) void scan3_k(const h2* __restrict__ Zh,
                                               const h2* __restrict__ Fh,
                                               const h2* __restrict__ Oh,
                                               const f2* __restrict__ Hs,
                                               float* __restrict__ Out) {
  const int idx = blockIdx.x * 256 + threadIdx.x;   // [b][c][hp]
  const int b = idx / (CH * HH2);
  const int r = idx - b * (CH * HH2);
  const int c = r / HH2;
  const int hp = r - c * HH2;
  f2 hs = Hs[((size_t)b * CH + c) * HH2 + hp];
  float h0v = hs[0], h1v = hs[1];
  size_t p = ((size_t)b * TT + (size_t)c * CL) * HH2 + hp;
#pragma unroll 8
  for (int t = 0; t < CL; ++t, p += HH2) {
    h2 f = Fh[p], z = Zh[p], o = Oh[p];
    h0v = fmaf((float)f[0], (float)z[0] - h0v, h0v);
    h1v = fmaf((float)f[1], (float)z[1] - h1v, h1v);
    f2 cv; cv[0] = (float)o[0] * h0v; cv[1] = (float)o[1] * h1v;
    __builtin_nontemporal_store(cv, (f2*)&Out[p * 2]);
  }
}

extern "C" void kernel_launch(void* const* d_in, const int* in_sizes, int n_in,
                              void* d_out, int out_size, void* d_ws, size_t ws_size,
                              hipStream_t stream) {
  const float* x    = (const float*)d_in[0];
  const float* W    = (const float*)d_in[1];
  const float* bias = (const float*)d_in[2];
  const float* h0   = (const float*)d_in[3];
  float* Out = (float*)d_out;
  char* ws = (char*)d_ws;

  // ws layout
  const size_t A_BYTES  = (size_t)MT2 * KTL * 16384;       // 104,857,600
  const size_t W_BYTES  = (size_t)NT * KTL * 8192;         //   5,529,600
  const size_t G_BYTES  = (size_t)MM * HH * 2;             // 150,994,944 per gate (fp16)
  const size_t PQ_BYTES = (size_t)BB * CH * HH2 * 16;      //   4,718,592
  unsigned short* Aws = (unsigned short*)ws;
  unsigned short* Wws = (unsigned short*)(ws + A_BYTES);
  _Float16* Zh = (_Float16*)(ws + A_BYTES + W_BYTES);
  _Float16* Fh = (_Float16*)(ws + A_BYTES + W_BYTES + G_BYTES);
  _Float16* Oh = (_Float16*)(ws + A_BYTES + W_BYTES + 2 * G_BYTES);
  f32x4* PQ = (f32x4*)(ws + A_BYTES + W_BYTES + 3 * G_BYTES);
  f2* Hs = (f2*)(ws + A_BYTES + W_BYTES + 3 * G_BYTES + PQ_BYTES);
  (void)ws_size; (void)in_sizes; (void)n_in; (void)out_size;

  pack_W_k<<<dim3(NT, KTL), 256, 0, stream>>>(W, Wws);
  pack_A_k<<<dim3(MT2, KTL), 256, 0, stream>>>(x, Aws);
  gemm_k<<<MT2 * NT, 512, 0, stream>>>(Aws, Wws, bias, Zh, Fh, Oh);
  scan1_k<<<BB * CH * HH2 / 256, 256, 0, stream>>>((const h2*)Zh, (const h2*)Fh, PQ);
  scan2_k<<<BB * HH2 / 256, 256, 0, stream>>>(PQ, h0, Hs);
  scan3_k<<<BB * CH * HH2 / 256, 256, 0, stream>>>((const h2*)Zh, (const h2*)Fh, (const h2*)Oh, Hs, Out);
}